// Round 5
// baseline (155.520 us; speedup 1.0000x reference)
//
#include <hip/hip_runtime.h>
#include <hip/hip_bf16.h>

// Problem constants (from reference):
// B=2, N=6, D=120, H=32, W=88, C=128, Z=1, HO=128, WO=128
#define HW_    2816
#define C_     128
#define BN_    12
#define SPAT_  16384
#define CELLS_ 32768
#define G_     16      // intervals per block (16 waves x 64 lanes = 1024 threads)

// ---------------------------------------------------------------------------
// feat [BN, C, HW] f32  ->  featT [BN, HW, C] bf16 (contiguous 256B per point)
// ---------------------------------------------------------------------------
__global__ __launch_bounds__(256) void transpose_feat_bf16_k(const float* __restrict__ feat,
                                                             __hip_bfloat16* __restrict__ featT) {
    __shared__ float tile[32][33];
    const int bn  = blockIdx.z;
    const int hw0 = blockIdx.x * 32;
    const int c0  = blockIdx.y * 32;
    const int x = threadIdx.x;   // 0..31
    const int y = threadIdx.y;   // 0..7

    const float* src = feat + ((size_t)bn * C_ + c0) * HW_ + hw0;
    #pragma unroll
    for (int yy = y; yy < 32; yy += 8)
        tile[yy][x] = src[(size_t)yy * HW_ + x];       // coalesced along hw
    __syncthreads();
    __hip_bfloat16* dst = featT + ((size_t)bn * HW_ + hw0) * C_ + c0;
    #pragma unroll
    for (int yy = y; yy < 32; yy += 8)
        dst[(size_t)yy * C_ + x] = __float2bfloat16(tile[x][yy]);  // coalesced along c
}

// ---------------------------------------------------------------------------
// Fused main: 16 waves per block, one interval per wave (intervals are sorted
// by bev cell -> a block's 16 cells are ~consecutive sp positions).
//  Gather phase (per wave): 4 groups of 16 lanes; lane owns 8 channels
//  (uint4 = bf16x8; 16 lanes x 16B = full 256B feature row). Group g owns
//  points i ≡ g (mod 4), unrolled x8 (slots i+4u) -> 8 feature-row + 8 depth
//  gathers in flight per wave. Tail slots clamp to the (valid) loop base and
//  multiply by d=0 (round-2/4-proven predication; no readlane).
//  Store phase: results staged in LDS [16][132] (pad -> 2-way conflict, free),
//  then cooperative store: for each channel, 16 consecutive cells = one 64B
//  line -> direct coalesced write to out [b,c,sp]. No cellbuf, no transpose.
// ---------------------------------------------------------------------------
__global__ __launch_bounds__(1024, 8) void bevpool_fused_k(const float* __restrict__ depth,
                                                           const uint4* __restrict__ featT,
                                                           const int* __restrict__ rd_arr,
                                                           const int* __restrict__ rf_arr,
                                                           const int* __restrict__ rb,
                                                           const int* __restrict__ istart,
                                                           const int* __restrict__ ilen,
                                                           float* __restrict__ out,
                                                           int n_intervals) {
    __shared__ float lds[G_][132];   // [interval][channel], pad 132: store 4-way (1 instr),
    __shared__ int   lds_cell[G_];   // read 2-way (free per m136)

    const int widx = threadIdx.x >> 6;    // 0..15: which interval of the block
    const int lane = threadIdx.x & 63;
    const int grp  = lane >> 4;           // 0..3: point residue class
    const int sl   = lane & 15;           // channel block: channels 8*sl .. 8*sl+7
    const int ivl  = blockIdx.x * G_ + widx;

    if (ivl < n_intervals) {
        const int start = istart[ivl];
        const int end   = start + ilen[ivl];

        float acc[8] = {0.f, 0.f, 0.f, 0.f, 0.f, 0.f, 0.f, 0.f};

        for (int i = start + grp; i < end; i += 32) {
            int   rd_[8], rf_[8];
            float d_[8];
            uint4 f_[8];
            // all index loads issued up front (8 rd + 8 rf, coalesced-ish)
            #pragma unroll
            for (int u = 0; u < 8; ++u) {
                const int ii = i + 4 * u;
                const int cl = (ii < end) ? ii : i;    // clamp to valid address
                rd_[u] = rd_arr[cl];
                rf_[u] = rf_arr[cl];
            }
            // 8 depth gathers in flight
            #pragma unroll
            for (int u = 0; u < 8; ++u) d_[u] = depth[rd_[u]];
            // predicate AFTER load (mul-by-0 tail); u=0 always valid
            #pragma unroll
            for (int u = 1; u < 8; ++u) d_[u] = (i + 4 * u < end) ? d_[u] : 0.f;
            // 8 feature-row gathers in flight (16 lanes x 16B = 256B per row)
            #pragma unroll
            for (int u = 0; u < 8; ++u) f_[u] = featT[(size_t)rf_[u] * (C_ / 8) + sl];
            #pragma unroll
            for (int u = 0; u < 8; ++u) {
                const float d = d_[u];
                acc[0] = fmaf(d, __uint_as_float(f_[u].x << 16),         acc[0]);
                acc[1] = fmaf(d, __uint_as_float(f_[u].x & 0xffff0000u), acc[1]);
                acc[2] = fmaf(d, __uint_as_float(f_[u].y << 16),         acc[2]);
                acc[3] = fmaf(d, __uint_as_float(f_[u].y & 0xffff0000u), acc[3]);
                acc[4] = fmaf(d, __uint_as_float(f_[u].z << 16),         acc[4]);
                acc[5] = fmaf(d, __uint_as_float(f_[u].z & 0xffff0000u), acc[5]);
                acc[6] = fmaf(d, __uint_as_float(f_[u].w << 16),         acc[6]);
                acc[7] = fmaf(d, __uint_as_float(f_[u].w & 0xffff0000u), acc[7]);
            }
        }

        // combine the 4 groups' partial sums (same channels, different points)
        #pragma unroll
        for (int c = 0; c < 8; ++c) {
            acc[c] += __shfl_down(acc[c], 32);
            acc[c] += __shfl_down(acc[c], 16);
        }

        if (grp == 0) {
            #pragma unroll
            for (int c = 0; c < 8; ++c) lds[widx][sl * 8 + c] = acc[c];
            if (sl == 0) lds_cell[widx] = rb[start];
        }
    }
    __syncthreads();

    // cooperative store: thread -> (channel c0(+64), interval j). For fixed
    // channel, 16 consecutive cells -> one 64B line (cells are sorted).
    const int j  = threadIdx.x & 15;
    const int c0 = threadIdx.x >> 4;          // 0..63
    const int nv = n_intervals - blockIdx.x * G_;
    if (j < nv) {
        const int cell = lds_cell[j];
        const int b  = cell >> 14;            // cell / SPAT_
        const int sp = cell & (SPAT_ - 1);    // cell % SPAT_
        float* o = out + (size_t)b * ((size_t)C_ * SPAT_) + sp;
        o[(size_t)c0        * SPAT_] = lds[j][c0];
        o[(size_t)(c0 + 64) * SPAT_] = lds[j][c0 + 64];
    }
}

// ---------------------------------------------------------------------------
// Fallback (ws too small): original-layout reads, scattered stores.
// ---------------------------------------------------------------------------
__global__ __launch_bounds__(256) void bevpool_fallback_k(const float* __restrict__ depth,
                                                          const float* __restrict__ feat,
                                                          const int* __restrict__ rd_arr,
                                                          const int* __restrict__ rf_arr,
                                                          const int* __restrict__ rb,
                                                          const int* __restrict__ istart,
                                                          const int* __restrict__ ilen,
                                                          float* __restrict__ out,
                                                          int n_intervals) {
    const int wave = (int)((blockIdx.x * blockDim.x + threadIdx.x) >> 6);
    const int lane = threadIdx.x & 63;
    if (wave >= n_intervals) return;
    const int start = istart[wave];
    const int len   = ilen[wave];
    const int cell  = rb[start];
    float ax = 0.f, ay = 0.f;
    const int end = start + len;
    for (int i = start; i < end; ++i) {
        const int rfi = rf_arr[i];
        const int bn  = rfi / HW_;
        const int hw  = rfi - bn * HW_;
        const float d = depth[rd_arr[i]];
        const float* frow = feat + (size_t)bn * (C_ * HW_) + hw;
        ax = fmaf(d, frow[(size_t)(2 * lane)     * HW_], ax);
        ay = fmaf(d, frow[(size_t)(2 * lane + 1) * HW_], ay);
    }
    const int b  = cell >> 14;
    const int sp = cell & (SPAT_ - 1);
    float* o = out + (size_t)b * ((size_t)C_ * SPAT_) + sp;
    o[(size_t)(2 * lane)     * SPAT_] = ax;
    o[(size_t)(2 * lane + 1) * SPAT_] = ay;
}

extern "C" void kernel_launch(void* const* d_in, const int* in_sizes, int n_in,
                              void* d_out, int out_size, void* d_ws, size_t ws_size,
                              hipStream_t stream) {
    const float* depth  = (const float*)d_in[0];
    const float* feat   = (const float*)d_in[1];
    const int*   rd     = (const int*)d_in[2];
    const int*   rf     = (const int*)d_in[3];
    const int*   rb     = (const int*)d_in[4];
    const int*   istart = (const int*)d_in[5];
    const int*   ilen   = (const int*)d_in[6];
    float*       out    = (float*)d_out;
    const int n_intervals = in_sizes[5];

    const size_t featT_bytes = (size_t)BN_ * HW_ * C_ * sizeof(__hip_bfloat16); // 8.65 MB

    // empty cells must be zero
    hipMemsetAsync(out, 0, (size_t)out_size * sizeof(float), stream);

    if (ws_size >= featT_bytes) {
        __hip_bfloat16* featT = (__hip_bfloat16*)d_ws;
        {
            dim3 g(HW_ / 32, C_ / 32, BN_);
            dim3 b(32, 8);
            transpose_feat_bf16_k<<<g, b, 0, stream>>>(feat, featT);
        }
        const int blocks = (n_intervals + G_ - 1) / G_;
        bevpool_fused_k<<<blocks, G_ * 64, 0, stream>>>(
            depth, (const uint4*)featT, rd, rf, rb, istart, ilen,
            out, n_intervals);
    } else {
        const int blocks = (n_intervals + 3) / 4;
        bevpool_fallback_k<<<blocks, 256, 0, stream>>>(
            depth, feat, rd, rf, rb, istart, ilen, out, n_intervals);
    }
}

// Round 6
// 77.430 us; speedup vs baseline: 2.0085x; 2.0085x over previous
//
#include <hip/hip_runtime.h>
#include <hip/hip_bf16.h>

// Problem constants (from reference):
// B=2, N=6, D=120, H=32, W=88, C=128, Z=1, HO=128, WO=128
#define HW_    2816
#define C_     128
#define BN_    12
#define SPAT_  16384
#define CELLS_ 32768

// ---------------------------------------------------------------------------
// feat [BN, C, HW] f32  ->  featT [BN, HW, C] bf16 (contiguous 256B per point)
// ---------------------------------------------------------------------------
__global__ __launch_bounds__(256) void transpose_feat_bf16_k(const float* __restrict__ feat,
                                                             __hip_bfloat16* __restrict__ featT) {
    __shared__ float tile[32][33];
    const int bn  = blockIdx.z;
    const int hw0 = blockIdx.x * 32;
    const int c0  = blockIdx.y * 32;
    const int x = threadIdx.x;   // 0..31
    const int y = threadIdx.y;   // 0..7

    const float* src = feat + ((size_t)bn * C_ + c0) * HW_ + hw0;
    #pragma unroll
    for (int yy = y; yy < 32; yy += 8)
        tile[yy][x] = src[(size_t)yy * HW_ + x];       // coalesced along hw
    __syncthreads();
    __hip_bfloat16* dst = featT + ((size_t)bn * HW_ + hw0) * C_ + c0;
    #pragma unroll
    for (int yy = y; yy < 32; yy += 8)
        dst[(size_t)yy * C_ + x] = __float2bfloat16(tile[x][yy]);  // coalesced along c
}

// ---------------------------------------------------------------------------
// Main: one wave per interval (4 waves / 256-thread block). 4 groups of 16
// lanes; lane owns 8 channels (uint4 = bf16x8; 16 lanes x 16B = full 256B
// feature row). Group g owns points i ≡ g (mod 4), 8 slots per iteration
// (stride 32). sched_barrier(0) fences after each load group force ALL 8
// depth + 8 feature gathers to be issued before the first FMA consumes them
// (r5 showed the scheduler otherwise serializes to ~2 in flight / 32 VGPR).
// Tail slots clamp to the valid loop base and multiply by d=0 (r2/r4-proven).
// Store: grp 0 writes float4 x2 -> 512B fully-contiguous per interval to
// cellbuf [cell][c] (r4-proven clean: WRITE == data; r5's segmented direct
// store was 17x write-amplified — never store disjoint 64B segments).
// ---------------------------------------------------------------------------
__global__ __launch_bounds__(256, 4) void bevpool_main32_k(const float* __restrict__ depth,
                                                           const uint4* __restrict__ featT,
                                                           const int* __restrict__ rd_arr,
                                                           const int* __restrict__ rf_arr,
                                                           const int* __restrict__ rb,
                                                           const int* __restrict__ istart,
                                                           const int* __restrict__ ilen,
                                                           float* __restrict__ cellbuf,
                                                           int n_intervals) {
    const int wave = (int)((blockIdx.x * blockDim.x + threadIdx.x) >> 6);
    if (wave >= n_intervals) return;
    const int lane = threadIdx.x & 63;
    const int grp  = lane >> 4;        // 0..3: point residue class
    const int sl   = lane & 15;        // channel block: channels 8*sl .. 8*sl+7

    const int start = istart[wave];
    const int end   = start + ilen[wave];
    const int cell  = rb[start];

    float acc[8] = {0.f, 0.f, 0.f, 0.f, 0.f, 0.f, 0.f, 0.f};

    for (int i = start + grp; i < end; i += 32) {
        int   rd_[8], rf_[8];
        float d_[8];
        uint4 f_[8];
        // group-uniform index loads, all issued up front
        #pragma unroll
        for (int u = 0; u < 8; ++u) {
            const int ii = i + 4 * u;
            const int cl = (ii < end) ? ii : i;    // clamp to valid address
            rd_[u] = rd_arr[cl];
            rf_[u] = rf_arr[cl];
        }
        __builtin_amdgcn_sched_barrier(0);          // keep index loads batched
        // 8 depth gathers in flight
        #pragma unroll
        for (int u = 0; u < 8; ++u) d_[u] = depth[rd_[u]];
        __builtin_amdgcn_sched_barrier(0);          // keep depth gathers batched
        // predicate AFTER load (mul-by-0 tail); u=0 always valid
        #pragma unroll
        for (int u = 1; u < 8; ++u) d_[u] = (i + 4 * u < end) ? d_[u] : 0.f;
        // 8 feature-row gathers in flight (16 lanes x 16B = 256B per row)
        #pragma unroll
        for (int u = 0; u < 8; ++u) f_[u] = featT[(size_t)rf_[u] * (C_ / 8) + sl];
        __builtin_amdgcn_sched_barrier(0);          // ALL 8 rows issued before first FMA
        #pragma unroll
        for (int u = 0; u < 8; ++u) {
            const float d = d_[u];
            acc[0] = fmaf(d, __uint_as_float(f_[u].x << 16),         acc[0]);
            acc[1] = fmaf(d, __uint_as_float(f_[u].x & 0xffff0000u), acc[1]);
            acc[2] = fmaf(d, __uint_as_float(f_[u].y << 16),         acc[2]);
            acc[3] = fmaf(d, __uint_as_float(f_[u].y & 0xffff0000u), acc[3]);
            acc[4] = fmaf(d, __uint_as_float(f_[u].z << 16),         acc[4]);
            acc[5] = fmaf(d, __uint_as_float(f_[u].z & 0xffff0000u), acc[5]);
            acc[6] = fmaf(d, __uint_as_float(f_[u].w << 16),         acc[6]);
            acc[7] = fmaf(d, __uint_as_float(f_[u].w & 0xffff0000u), acc[7]);
        }
    }

    // combine the 4 groups' partial sums (same channels, different points)
    #pragma unroll
    for (int c = 0; c < 8; ++c) {
        acc[c] += __shfl_down(acc[c], 32);
        acc[c] += __shfl_down(acc[c], 16);
    }

    if (grp == 0) {
        float4* o = (float4*)(cellbuf + (size_t)cell * C_ + sl * 8);
        o[0] = make_float4(acc[0], acc[1], acc[2], acc[3]);   // 512B contiguous/interval
        o[1] = make_float4(acc[4], acc[5], acc[6], acc[7]);
    }
}

// ---------------------------------------------------------------------------
// cellbuf [B, SPAT, C] f32 -> out [B, C, SPAT] f32 (both sides coalesced)
// ---------------------------------------------------------------------------
__global__ __launch_bounds__(256) void transpose_out_k(const float* __restrict__ cellbuf,
                                                       float* __restrict__ out) {
    __shared__ float tile[32][33];
    const int b   = blockIdx.z;
    const int sp0 = blockIdx.x * 32;
    const int c0  = blockIdx.y * 32;
    const int x = threadIdx.x;
    const int y = threadIdx.y;

    const float* src = cellbuf + ((size_t)b * SPAT_ + sp0) * C_ + c0;
    #pragma unroll
    for (int yy = y; yy < 32; yy += 8)
        tile[yy][x] = src[(size_t)yy * C_ + x];
    __syncthreads();
    float* dst = out + ((size_t)b * C_ + c0) * SPAT_ + sp0;
    #pragma unroll
    for (int yy = y; yy < 32; yy += 8)
        dst[(size_t)yy * SPAT_ + x] = tile[x][yy];
}

// ---------------------------------------------------------------------------
// Fallback (ws too small): original-layout reads, scattered stores.
// ---------------------------------------------------------------------------
__global__ __launch_bounds__(256) void bevpool_fallback_k(const float* __restrict__ depth,
                                                          const float* __restrict__ feat,
                                                          const int* __restrict__ rd_arr,
                                                          const int* __restrict__ rf_arr,
                                                          const int* __restrict__ rb,
                                                          const int* __restrict__ istart,
                                                          const int* __restrict__ ilen,
                                                          float* __restrict__ out,
                                                          int n_intervals) {
    const int wave = (int)((blockIdx.x * blockDim.x + threadIdx.x) >> 6);
    const int lane = threadIdx.x & 63;
    if (wave >= n_intervals) return;
    const int start = istart[wave];
    const int len   = ilen[wave];
    const int cell  = rb[start];
    float ax = 0.f, ay = 0.f;
    const int end = start + len;
    for (int i = start; i < end; ++i) {
        const int rfi = rf_arr[i];
        const int bn  = rfi / HW_;
        const int hw  = rfi - bn * HW_;
        const float d = depth[rd_arr[i]];
        const float* frow = feat + (size_t)bn * (C_ * HW_) + hw;
        ax = fmaf(d, frow[(size_t)(2 * lane)     * HW_], ax);
        ay = fmaf(d, frow[(size_t)(2 * lane + 1) * HW_], ay);
    }
    const int b  = cell >> 14;
    const int sp = cell & (SPAT_ - 1);
    float* o = out + (size_t)b * ((size_t)C_ * SPAT_) + sp;
    o[(size_t)(2 * lane)     * SPAT_] = ax;
    o[(size_t)(2 * lane + 1) * SPAT_] = ay;
}

extern "C" void kernel_launch(void* const* d_in, const int* in_sizes, int n_in,
                              void* d_out, int out_size, void* d_ws, size_t ws_size,
                              hipStream_t stream) {
    const float* depth  = (const float*)d_in[0];
    const float* feat   = (const float*)d_in[1];
    const int*   rd     = (const int*)d_in[2];
    const int*   rf     = (const int*)d_in[3];
    const int*   rb     = (const int*)d_in[4];
    const int*   istart = (const int*)d_in[5];
    const int*   ilen   = (const int*)d_in[6];
    float*       out    = (float*)d_out;
    const int n_intervals = in_sizes[5];

    const size_t cellbuf_bytes = (size_t)CELLS_ * C_ * sizeof(float);             // 16.78 MB
    const size_t featT_bytes   = (size_t)BN_ * HW_ * C_ * sizeof(__hip_bfloat16); // 8.65 MB
    const int blocks = (n_intervals + 3) / 4;   // 4 waves per 256-thread block

    if (ws_size >= cellbuf_bytes + featT_bytes) {
        float*          cellbuf = (float*)d_ws;
        __hip_bfloat16* featT   = (__hip_bfloat16*)((char*)d_ws + cellbuf_bytes);
        hipMemsetAsync(cellbuf, 0, cellbuf_bytes, stream);   // empty cells -> 0
        {
            dim3 g(HW_ / 32, C_ / 32, BN_);
            dim3 b(32, 8);
            transpose_feat_bf16_k<<<g, b, 0, stream>>>(feat, featT);
        }
        bevpool_main32_k<<<blocks, 256, 0, stream>>>(
            depth, (const uint4*)featT, rd, rf, rb, istart, ilen,
            cellbuf, n_intervals);
        {
            dim3 g(SPAT_ / 32, C_ / 32, 2);
            dim3 b(32, 8);
            transpose_out_k<<<g, b, 0, stream>>>(cellbuf, out);
        }
    } else {
        hipMemsetAsync(out, 0, (size_t)out_size * sizeof(float), stream);
        bevpool_fallback_k<<<blocks, 256, 0, stream>>>(
            depth, feat, rd, rf, rb, istart, ilen, out, n_intervals);
    }
}

// Round 7
// 72.552 us; speedup vs baseline: 2.1436x; 1.0672x over previous
//
#include <hip/hip_runtime.h>
#include <hip/hip_bf16.h>

// Problem constants (from reference):
// B=2, N=6, D=120, H=32, W=88, C=128, Z=1, HO=128, WO=128
#define HW_    2816
#define C_     128
#define BN_    12
#define SPAT_  16384
#define CELLS_ 32768

// round-to-nearest-even f32 -> bf16 (as uint in [0,0xffff]); values are finite
__device__ __forceinline__ unsigned int f2bf_rne(float x) {
    const unsigned int u = __float_as_uint(x);
    return (u + 0x7fffu + ((u >> 16) & 1u)) >> 16;
}

// ---------------------------------------------------------------------------
// feat [BN, C, HW] f32  ->  featT [BN, HW, C] bf16 (contiguous 256B per point)
// ---------------------------------------------------------------------------
__global__ __launch_bounds__(256) void transpose_feat_bf16_k(const float* __restrict__ feat,
                                                             __hip_bfloat16* __restrict__ featT) {
    __shared__ float tile[32][33];
    const int bn  = blockIdx.z;
    const int hw0 = blockIdx.x * 32;
    const int c0  = blockIdx.y * 32;
    const int x = threadIdx.x;   // 0..31
    const int y = threadIdx.y;   // 0..7

    const float* src = feat + ((size_t)bn * C_ + c0) * HW_ + hw0;
    #pragma unroll
    for (int yy = y; yy < 32; yy += 8)
        tile[yy][x] = src[(size_t)yy * HW_ + x];       // coalesced along hw
    __syncthreads();
    __hip_bfloat16* dst = featT + ((size_t)bn * HW_ + hw0) * C_ + c0;
    #pragma unroll
    for (int yy = y; yy < 32; yy += 8)
        dst[(size_t)yy * C_ + x] = __float2bfloat16(tile[x][yy]);  // coalesced along c
}

// ---------------------------------------------------------------------------
// Depth pre-gather: dper[i] = depth[rd[i]] (contiguous result). Pays the
// unavoidable random-line depth cost ONCE; main passes then read coalesced.
// 4 independent gathers in flight per thread.
// ---------------------------------------------------------------------------
__global__ __launch_bounds__(256) void depth_pregather_k(const float* __restrict__ depth,
                                                         const int* __restrict__ rd,
                                                         float* __restrict__ dper, int n) {
    const int tid    = blockIdx.x * 256 + threadIdx.x;
    const int stride = gridDim.x * 256;
    for (int base = tid; base < n; base += 4 * stride) {
        int ii[4], idx[4];
        float v[4];
        #pragma unroll
        for (int u = 0; u < 4; ++u) {
            ii[u] = base + u * stride;
            idx[u] = rd[ii[u] < n ? ii[u] : base];     // clamp to valid address
        }
        #pragma unroll
        for (int u = 0; u < 4; ++u) v[u] = depth[idx[u]];
        #pragma unroll
        for (int u = 0; u < 4; ++u) if (ii[u] < n) dper[ii[u]] = v[u];
    }
}

// ---------------------------------------------------------------------------
// Main: TWO blocks per interval group — half = blockIdx.x & 1 selects which
// 64 channels. Since blockIdx round-robins across the 8 XCDs (b%8), even
// blocks (half 0) run on even XCDs, odd on odd -> each XCD only gathers from
// a 4.33 MB featT half-table, which FITS its private 4 MB L2 (vs 8.65 MB
// thrashing it: r4/r6 showed 157 MB FETCH ~= time*3.5TB/s, traffic-bound).
// Wrong-mapping worst case: perf falls back to r4 levels; never incorrect.
// Per wave: 8 groups x 8 lanes; lane owns 8 channels of its half (uint4 =
// bf16x8, 8 lanes x 16B = 128B half-row). Group g owns points i = g (mod 8),
// 4 slots per iteration (stride 32) -> 4 half-row + 4 depth reads in flight.
// Depth now from dper (contiguous). Tail: clamp addr, multiply by 0.
// Store: grp 0 packs bf16x8 -> one uint4 -> 128B contiguous per (ivl,half).
// ---------------------------------------------------------------------------
__global__ __launch_bounds__(256) void bevpool_half_k(const float* __restrict__ dper,
                                                      const uint4* __restrict__ featT,
                                                      const int* __restrict__ rf_arr,
                                                      const int* __restrict__ rb,
                                                      const int* __restrict__ istart,
                                                      const int* __restrict__ ilen,
                                                      unsigned short* __restrict__ cellbuf,
                                                      int n_intervals) {
    const int half = blockIdx.x & 1;
    const int widx = threadIdx.x >> 6;             // 0..3
    const int ivl  = (blockIdx.x >> 1) * 4 + widx; // interval
    if (ivl >= n_intervals) return;
    const int lane = threadIdx.x & 63;
    const int grp  = lane >> 3;        // 0..7: point residue class (mod 8)
    const int sl   = lane & 7;         // channel chunk within half: 8*sl..8*sl+7

    const int start = istart[ivl];
    const int end   = start + ilen[ivl];
    const int cell  = rb[start];

    float acc[8] = {0.f, 0.f, 0.f, 0.f, 0.f, 0.f, 0.f, 0.f};
    const size_t hoff = (size_t)(half * 8 + sl);   // uint4 offset within a 256B row

    for (int i = start + grp; i < end; i += 32) {
        int cl_[4], rf_[4];
        float d_[4];
        uint4 f_[4];
        #pragma unroll
        for (int u = 0; u < 4; ++u) {
            const int ii = i + 8 * u;
            cl_[u] = (ii < end) ? ii : i;          // clamp to valid address
        }
        #pragma unroll
        for (int u = 0; u < 4; ++u) rf_[u] = rf_arr[cl_[u]];   // 8 consecutive addrs/wave
        #pragma unroll
        for (int u = 0; u < 4; ++u) d_[u] = dper[cl_[u]];      // contiguous, broadcast/group
        #pragma unroll
        for (int u = 1; u < 4; ++u) d_[u] = (i + 8 * u < end) ? d_[u] : 0.f;
        #pragma unroll
        for (int u = 0; u < 4; ++u) f_[u] = featT[(size_t)rf_[u] * 16 + hoff];
        #pragma unroll
        for (int u = 0; u < 4; ++u) {
            const float d = d_[u];
            acc[0] = fmaf(d, __uint_as_float(f_[u].x << 16),         acc[0]);
            acc[1] = fmaf(d, __uint_as_float(f_[u].x & 0xffff0000u), acc[1]);
            acc[2] = fmaf(d, __uint_as_float(f_[u].y << 16),         acc[2]);
            acc[3] = fmaf(d, __uint_as_float(f_[u].y & 0xffff0000u), acc[3]);
            acc[4] = fmaf(d, __uint_as_float(f_[u].z << 16),         acc[4]);
            acc[5] = fmaf(d, __uint_as_float(f_[u].z & 0xffff0000u), acc[5]);
            acc[6] = fmaf(d, __uint_as_float(f_[u].w << 16),         acc[6]);
            acc[7] = fmaf(d, __uint_as_float(f_[u].w & 0xffff0000u), acc[7]);
        }
    }

    // combine the 8 groups' partial sums (same channels, different points)
    #pragma unroll
    for (int c = 0; c < 8; ++c) {
        acc[c] += __shfl_down(acc[c], 32);
        acc[c] += __shfl_down(acc[c], 16);
        acc[c] += __shfl_down(acc[c], 8);
    }

    if (grp == 0) {
        uint4 p;
        p.x = f2bf_rne(acc[0]) | (f2bf_rne(acc[1]) << 16);
        p.y = f2bf_rne(acc[2]) | (f2bf_rne(acc[3]) << 16);
        p.z = f2bf_rne(acc[4]) | (f2bf_rne(acc[5]) << 16);
        p.w = f2bf_rne(acc[6]) | (f2bf_rne(acc[7]) << 16);
        // 8 lanes x 16B = 128B contiguous per (interval, half) — proven-clean pattern
        *(uint4*)(cellbuf + (size_t)cell * C_ + half * 64 + sl * 8) = p;
    }
}

// ---------------------------------------------------------------------------
// cellbuf [B, SPAT, C] bf16 -> out [B, C, SPAT] f32 (both sides coalesced)
// ---------------------------------------------------------------------------
__global__ __launch_bounds__(256) void transpose_out_bf16_k(const unsigned short* __restrict__ cellbuf,
                                                            float* __restrict__ out) {
    __shared__ float tile[32][33];
    const int b   = blockIdx.z;
    const int sp0 = blockIdx.x * 32;
    const int c0  = blockIdx.y * 32;
    const int x = threadIdx.x;
    const int y = threadIdx.y;

    const unsigned short* src = cellbuf + ((size_t)b * SPAT_ + sp0) * C_ + c0;
    #pragma unroll
    for (int yy = y; yy < 32; yy += 8)
        tile[yy][x] = __uint_as_float((unsigned int)src[(size_t)yy * C_ + x] << 16);
    __syncthreads();
    float* dst = out + ((size_t)b * C_ + c0) * SPAT_ + sp0;
    #pragma unroll
    for (int yy = y; yy < 32; yy += 8)
        dst[(size_t)yy * SPAT_ + x] = tile[x][yy];   // 128B contiguous per row
}

// ---------------------------------------------------------------------------
// Fallback (ws too small): original-layout reads, scattered stores.
// ---------------------------------------------------------------------------
__global__ __launch_bounds__(256) void bevpool_fallback_k(const float* __restrict__ depth,
                                                          const float* __restrict__ feat,
                                                          const int* __restrict__ rd_arr,
                                                          const int* __restrict__ rf_arr,
                                                          const int* __restrict__ rb,
                                                          const int* __restrict__ istart,
                                                          const int* __restrict__ ilen,
                                                          float* __restrict__ out,
                                                          int n_intervals) {
    const int wave = (int)((blockIdx.x * blockDim.x + threadIdx.x) >> 6);
    const int lane = threadIdx.x & 63;
    if (wave >= n_intervals) return;
    const int start = istart[wave];
    const int len   = ilen[wave];
    const int cell  = rb[start];
    float ax = 0.f, ay = 0.f;
    const int end = start + len;
    for (int i = start; i < end; ++i) {
        const int rfi = rf_arr[i];
        const int bn  = rfi / HW_;
        const int hw  = rfi - bn * HW_;
        const float d = depth[rd_arr[i]];
        const float* frow = feat + (size_t)bn * (C_ * HW_) + hw;
        ax = fmaf(d, frow[(size_t)(2 * lane)     * HW_], ax);
        ay = fmaf(d, frow[(size_t)(2 * lane + 1) * HW_], ay);
    }
    const int b  = cell >> 14;
    const int sp = cell & (SPAT_ - 1);
    float* o = out + (size_t)b * ((size_t)C_ * SPAT_) + sp;
    o[(size_t)(2 * lane)     * SPAT_] = ax;
    o[(size_t)(2 * lane + 1) * SPAT_] = ay;
}

extern "C" void kernel_launch(void* const* d_in, const int* in_sizes, int n_in,
                              void* d_out, int out_size, void* d_ws, size_t ws_size,
                              hipStream_t stream) {
    const float* depth  = (const float*)d_in[0];
    const float* feat   = (const float*)d_in[1];
    const int*   rd     = (const int*)d_in[2];
    const int*   rf     = (const int*)d_in[3];
    const int*   rb     = (const int*)d_in[4];
    const int*   istart = (const int*)d_in[5];
    const int*   ilen   = (const int*)d_in[6];
    float*       out    = (float*)d_out;
    const int n_intervals = in_sizes[5];
    const int n_points    = in_sizes[2];

    const size_t cellbuf_bytes = (size_t)CELLS_ * C_ * sizeof(unsigned short);    // 8.39 MB
    const size_t featT_bytes   = (size_t)BN_ * HW_ * C_ * sizeof(__hip_bfloat16); // 8.65 MB
    const size_t dper_bytes    = (size_t)n_points * sizeof(float);                // 4.00 MB

    if (ws_size >= cellbuf_bytes + featT_bytes + dper_bytes) {
        unsigned short* cellbuf = (unsigned short*)d_ws;
        __hip_bfloat16* featT   = (__hip_bfloat16*)((char*)d_ws + cellbuf_bytes);
        float*          dper    = (float*)((char*)d_ws + cellbuf_bytes + featT_bytes);

        hipMemsetAsync(cellbuf, 0, cellbuf_bytes, stream);   // empty cells -> 0
        {
            dim3 g(HW_ / 32, C_ / 32, BN_);
            dim3 b(32, 8);
            transpose_feat_bf16_k<<<g, b, 0, stream>>>(feat, featT);
        }
        depth_pregather_k<<<1024, 256, 0, stream>>>(depth, rd, dper, n_points);

        const int blocks2 = 2 * ((n_intervals + 3) / 4);   // (interval-group, half) pairs
        bevpool_half_k<<<blocks2, 256, 0, stream>>>(
            dper, (const uint4*)featT, rf, rb, istart, ilen, cellbuf, n_intervals);
        {
            dim3 g(SPAT_ / 32, C_ / 32, 2);
            dim3 b(32, 8);
            transpose_out_bf16_k<<<g, b, 0, stream>>>(cellbuf, out);
        }
    } else {
        hipMemsetAsync(out, 0, (size_t)out_size * sizeof(float), stream);
        const int blocks = (n_intervals + 3) / 4;
        bevpool_fallback_k<<<blocks, 256, 0, stream>>>(
            depth, feat, rd, rf, rb, istart, ilen, out, n_intervals);
    }
}

// Round 9
// 71.857 us; speedup vs baseline: 2.1643x; 1.0097x over previous
//
#include <hip/hip_runtime.h>
#include <hip/hip_bf16.h>

// Problem constants (from reference):
// B=2, N=6, D=120, H=32, W=88, C=128, Z=1, HO=128, WO=128
#define HW_    2816
#define C_     128
#define BN_    12
#define SPAT_  16384
#define CELLS_ 32768

// round-to-nearest-even f32 -> bf16 (as uint in [0,0xffff]); values are finite
__device__ __forceinline__ unsigned int f2bf_rne(float x) {
    const unsigned int u = __float_as_uint(x);
    return (u + 0x7fffu + ((u >> 16) & 1u)) >> 16;
}

// ---------------------------------------------------------------------------
// Fast zero-fill (r7 lesson: rocclr fillBuffer runs at ~200 GB/s, 42us for
// 8.4MB; this grid-stride uint4 kernel does it in ~2us).
// ---------------------------------------------------------------------------
__global__ __launch_bounds__(256) void zero_buf_k(uint4* __restrict__ p, size_t n16) {
    size_t i = (size_t)blockIdx.x * 256 + threadIdx.x;
    const size_t stride = (size_t)gridDim.x * 256;
    for (; i < n16; i += stride) p[i] = make_uint4(0u, 0u, 0u, 0u);
}

// ---------------------------------------------------------------------------
// feat [BN, C, HW] f32  ->  featT [BN, HW, C] bf16 (contiguous 256B per point)
// ---------------------------------------------------------------------------
__global__ __launch_bounds__(256) void transpose_feat_bf16_k(const float* __restrict__ feat,
                                                             __hip_bfloat16* __restrict__ featT) {
    __shared__ float tile[32][33];
    const int bn  = blockIdx.z;
    const int hw0 = blockIdx.x * 32;
    const int c0  = blockIdx.y * 32;
    const int x = threadIdx.x;   // 0..31
    const int y = threadIdx.y;   // 0..7

    const float* src = feat + ((size_t)bn * C_ + c0) * HW_ + hw0;
    #pragma unroll
    for (int yy = y; yy < 32; yy += 8)
        tile[yy][x] = src[(size_t)yy * HW_ + x];       // coalesced along hw
    __syncthreads();
    __hip_bfloat16* dst = featT + ((size_t)bn * HW_ + hw0) * C_ + c0;
    #pragma unroll
    for (int yy = y; yy < 32; yy += 8)
        dst[(size_t)yy * C_ + x] = __float2bfloat16(tile[x][yy]);  // coalesced along c
}

// ---------------------------------------------------------------------------
// Depth pre-gather: dper[i] = depth[rd[i]] (contiguous result). Pays the
// unavoidable random-line depth cost ONCE; main passes then read coalesced.
// ---------------------------------------------------------------------------
__global__ __launch_bounds__(256) void depth_pregather_k(const float* __restrict__ depth,
                                                         const int* __restrict__ rd,
                                                         float* __restrict__ dper, int n) {
    const int tid    = blockIdx.x * 256 + threadIdx.x;
    const int stride = gridDim.x * 256;
    for (int base = tid; base < n; base += 4 * stride) {
        int ii[4], idx[4];
        float v[4];
        #pragma unroll
        for (int u = 0; u < 4; ++u) {
            ii[u] = base + u * stride;
            idx[u] = rd[ii[u] < n ? ii[u] : base];     // clamp to valid address
        }
        #pragma unroll
        for (int u = 0; u < 4; ++u) v[u] = depth[idx[u]];
        #pragma unroll
        for (int u = 0; u < 4; ++u) if (ii[u] < n) dper[ii[u]] = v[u];
    }
}

// ---------------------------------------------------------------------------
// Main: TWO blocks per interval group — half = blockIdx.x & 1 selects which
// 64 channels. blockIdx round-robins across the 8 XCDs, so each XCD only
// gathers from a 4.33 MB featT half-table -> fits its private 4 MB L2
// (r7-proven: main kernel dropped out of the top-5, from 51us).
// Per wave: 8 groups x 8 lanes; lane owns 8 channels of its half (uint4 =
// bf16x8, 8 lanes x 16B = 128B half-row). Group g owns points i = g (mod 8),
// 4 slots per iteration (stride 32). Depth from dper (contiguous).
// Tail: clamp addr, multiply by 0. Store: grp 0 packs bf16x8 -> one uint4 ->
// 128B contiguous per (ivl, half).
// ---------------------------------------------------------------------------
__global__ __launch_bounds__(256) void bevpool_half_k(const float* __restrict__ dper,
                                                      const uint4* __restrict__ featT,
                                                      const int* __restrict__ rf_arr,
                                                      const int* __restrict__ rb,
                                                      const int* __restrict__ istart,
                                                      const int* __restrict__ ilen,
                                                      unsigned short* __restrict__ cellbuf,
                                                      int n_intervals) {
    const int half = blockIdx.x & 1;
    const int widx = threadIdx.x >> 6;             // 0..3
    const int ivl  = (blockIdx.x >> 1) * 4 + widx; // interval
    if (ivl >= n_intervals) return;
    const int lane = threadIdx.x & 63;
    const int grp  = lane >> 3;        // 0..7: point residue class (mod 8)
    const int sl   = lane & 7;         // channel chunk within half: 8*sl..8*sl+7

    const int start = istart[ivl];
    const int end   = start + ilen[ivl];
    const int cell  = rb[start];

    float acc[8] = {0.f, 0.f, 0.f, 0.f, 0.f, 0.f, 0.f, 0.f};
    const size_t hoff = (size_t)(half * 8 + sl);   // uint4 offset within a 256B row

    for (int i = start + grp; i < end; i += 32) {
        int cl_[4], rf_[4];
        float d_[4];
        uint4 f_[4];
        #pragma unroll
        for (int u = 0; u < 4; ++u) {
            const int ii = i + 8 * u;
            cl_[u] = (ii < end) ? ii : i;          // clamp to valid address
        }
        #pragma unroll
        for (int u = 0; u < 4; ++u) rf_[u] = rf_arr[cl_[u]];   // 8 consecutive addrs/wave
        #pragma unroll
        for (int u = 0; u < 4; ++u) d_[u] = dper[cl_[u]];      // contiguous, broadcast/group
        #pragma unroll
        for (int u = 1; u < 4; ++u) d_[u] = (i + 8 * u < end) ? d_[u] : 0.f;
        #pragma unroll
        for (int u = 0; u < 4; ++u) f_[u] = featT[(size_t)rf_[u] * 16 + hoff];
        #pragma unroll
        for (int u = 0; u < 4; ++u) {
            const float d = d_[u];
            acc[0] = fmaf(d, __uint_as_float(f_[u].x << 16),         acc[0]);
            acc[1] = fmaf(d, __uint_as_float(f_[u].x & 0xffff0000u), acc[1]);
            acc[2] = fmaf(d, __uint_as_float(f_[u].y << 16),         acc[2]);
            acc[3] = fmaf(d, __uint_as_float(f_[u].y & 0xffff0000u), acc[3]);
            acc[4] = fmaf(d, __uint_as_float(f_[u].z << 16),         acc[4]);
            acc[5] = fmaf(d, __uint_as_float(f_[u].z & 0xffff0000u), acc[5]);
            acc[6] = fmaf(d, __uint_as_float(f_[u].w << 16),         acc[6]);
            acc[7] = fmaf(d, __uint_as_float(f_[u].w & 0xffff0000u), acc[7]);
        }
    }

    // combine the 8 groups' partial sums (same channels, different points)
    #pragma unroll
    for (int c = 0; c < 8; ++c) {
        acc[c] += __shfl_down(acc[c], 32);
        acc[c] += __shfl_down(acc[c], 16);
        acc[c] += __shfl_down(acc[c], 8);
    }

    if (grp == 0) {
        uint4 p;
        p.x = f2bf_rne(acc[0]) | (f2bf_rne(acc[1]) << 16);
        p.y = f2bf_rne(acc[2]) | (f2bf_rne(acc[3]) << 16);
        p.z = f2bf_rne(acc[4]) | (f2bf_rne(acc[5]) << 16);
        p.w = f2bf_rne(acc[6]) | (f2bf_rne(acc[7]) << 16);
        // 8 lanes x 16B = 128B contiguous per (interval, half) — proven-clean pattern
        *(uint4*)(cellbuf + (size_t)cell * C_ + half * 64 + sl * 8) = p;
    }
}

// ---------------------------------------------------------------------------
// cellbuf [B, SPAT, C] bf16 -> out [B, C, SPAT] f32 (both sides coalesced)
// ---------------------------------------------------------------------------
__global__ __launch_bounds__(256) void transpose_out_bf16_k(const unsigned short* __restrict__ cellbuf,
                                                            float* __restrict__ out) {
    __shared__ float tile[32][33];
    const int b   = blockIdx.z;
    const int sp0 = blockIdx.x * 32;
    const int c0  = blockIdx.y * 32;
    const int x = threadIdx.x;
    const int y = threadIdx.y;

    const unsigned short* src = cellbuf + ((size_t)b * SPAT_ + sp0) * C_ + c0;
    #pragma unroll
    for (int yy = y; yy < 32; yy += 8)
        tile[yy][x] = __uint_as_float((unsigned int)src[(size_t)yy * C_ + x] << 16);
    __syncthreads();
    float* dst = out + ((size_t)b * C_ + c0) * SPAT_ + sp0;
    #pragma unroll
    for (int yy = y; yy < 32; yy += 8)
        dst[(size_t)yy * SPAT_ + x] = tile[x][yy];   // 128B contiguous per row
}

// ---------------------------------------------------------------------------
// Fallback (ws too small): original-layout reads, scattered stores.
// ---------------------------------------------------------------------------
__global__ __launch_bounds__(256) void bevpool_fallback_k(const float* __restrict__ depth,
                                                          const float* __restrict__ feat,
                                                          const int* __restrict__ rd_arr,
                                                          const int* __restrict__ rf_arr,
                                                          const int* __restrict__ rb,
                                                          const int* __restrict__ istart,
                                                          const int* __restrict__ ilen,
                                                          float* __restrict__ out,
                                                          int n_intervals) {
    const int wave = (int)((blockIdx.x * blockDim.x + threadIdx.x) >> 6);
    const int lane = threadIdx.x & 63;
    if (wave >= n_intervals) return;
    const int start = istart[wave];
    const int len   = ilen[wave];
    const int cell  = rb[start];
    float ax = 0.f, ay = 0.f;
    const int end = start + len;
    for (int i = start; i < end; ++i) {
        const int rfi = rf_arr[i];
        const int bn  = rfi / HW_;
        const int hw  = rfi - bn * HW_;
        const float d = depth[rd_arr[i]];
        const float* frow = feat + (size_t)bn * (C_ * HW_) + hw;
        ax = fmaf(d, frow[(size_t)(2 * lane)     * HW_], ax);
        ay = fmaf(d, frow[(size_t)(2 * lane + 1) * HW_], ay);
    }
    const int b  = cell >> 14;
    const int sp = cell & (SPAT_ - 1);
    float* o = out + (size_t)b * ((size_t)C_ * SPAT_) + sp;
    o[(size_t)(2 * lane)     * SPAT_] = ax;
    o[(size_t)(2 * lane + 1) * SPAT_] = ay;
}

extern "C" void kernel_launch(void* const* d_in, const int* in_sizes, int n_in,
                              void* d_out, int out_size, void* d_ws, size_t ws_size,
                              hipStream_t stream) {
    const float* depth  = (const float*)d_in[0];
    const float* feat   = (const float*)d_in[1];
    const int*   rd     = (const int*)d_in[2];
    const int*   rf     = (const int*)d_in[3];
    const int*   rb     = (const int*)d_in[4];
    const int*   istart = (const int*)d_in[5];
    const int*   ilen   = (const int*)d_in[6];
    float*       out    = (float*)d_out;
    const int n_intervals = in_sizes[5];
    const int n_points    = in_sizes[2];

    const size_t cellbuf_bytes = (size_t)CELLS_ * C_ * sizeof(unsigned short);    // 8.39 MB
    const size_t featT_bytes   = (size_t)BN_ * HW_ * C_ * sizeof(__hip_bfloat16); // 8.65 MB
    const size_t dper_bytes    = (size_t)n_points * sizeof(float);                // 4.00 MB

    if (ws_size >= cellbuf_bytes + featT_bytes + dper_bytes) {
        unsigned short* cellbuf = (unsigned short*)d_ws;
        __hip_bfloat16* featT   = (__hip_bfloat16*)((char*)d_ws + cellbuf_bytes);
        float*          dper    = (float*)((char*)d_ws + cellbuf_bytes + featT_bytes);

        // empty cells -> 0 (custom kernel: rocclr fill is ~200 GB/s, r7 lesson)
        zero_buf_k<<<2048, 256, 0, stream>>>((uint4*)cellbuf, cellbuf_bytes / 16);
        {
            dim3 g(HW_ / 32, C_ / 32, BN_);
            dim3 b(32, 8);
            transpose_feat_bf16_k<<<g, b, 0, stream>>>(feat, featT);
        }
        depth_pregather_k<<<1024, 256, 0, stream>>>(depth, rd, dper, n_points);

        const int blocks2 = 2 * ((n_intervals + 3) / 4);   // (interval-group, half) pairs
        bevpool_half_k<<<blocks2, 256, 0, stream>>>(
            dper, (const uint4*)featT, rf, rb, istart, ilen, cellbuf, n_intervals);
        {
            dim3 g(SPAT_ / 32, C_ / 32, 2);
            dim3 b(32, 8);
            transpose_out_bf16_k<<<g, b, 0, stream>>>(cellbuf, out);
        }
    } else {
        hipMemsetAsync(out, 0, (size_t)out_size * sizeof(float), stream);
        const int blocks = (n_intervals + 3) / 4;
        bevpool_fallback_k<<<blocks, 256, 0, stream>>>(
            depth, feat, rd, rf, rb, istart, ilen, out, n_intervals);
    }
}

// Round 10
// 63.317 us; speedup vs baseline: 2.4562x; 1.1349x over previous
//
#include <hip/hip_runtime.h>
#include <hip/hip_bf16.h>

// Problem constants (from reference):
// B=2, N=6, D=120, H=32, W=88, C=128, Z=1, HO=128, WO=128
#define HW_    2816
#define C_     128
#define BN_    12
#define SPAT_  16384
#define CELLS_ 32768

// prep_k block-range dispatch
#define TF_BX     88                       // HW_/32
#define TF_BY     4                        // C_/32
#define TF_BLOCKS (TF_BX * TF_BY * BN_)    // 4224 transpose tiles
#define PG_BLOCKS 1024                     // pregather/pack
#define IV_BLOCKS 128                      // 128*256 = 32768 >= n_intervals
#define ZB_BLOCKS 512                      // cellbuf zero

// round-to-nearest-even f32 -> bf16 (as uint in [0,0xffff]); finite values
__device__ __forceinline__ unsigned int f2bf_rne(float x) {
    const unsigned int u = __float_as_uint(x);
    return (u + 0x7fffu + ((u >> 16) & 1u)) >> 16;
}

// ---------------------------------------------------------------------------
// Fused prep (r9 lesson: small kernels cost launches + ramp; fuse independent
// phases by blockIdx range):
//   [0, TF)        feat [BN,C,HW] f32 -> featT [BN,HW,C] bf16
//   [TF, TF+PG)    pair[i] = bf16(depth[rd[i]])<<16 | rf[i]  (rf < 33792 fits u16)
//   [.., +IV)      iv4[ivl] = {start, len, cell=rb[start], 0}  (kills the
//                  istart->ilen->rb dependent chain in the main kernel)
//   [.., +ZB)      zero cellbuf (custom: rocclr fill is slow, r7)
// ---------------------------------------------------------------------------
__global__ __launch_bounds__(256) void prep_k(
        const float* __restrict__ feat, __hip_bfloat16* __restrict__ featT,
        const float* __restrict__ depth, const int* __restrict__ rd,
        const int* __restrict__ rf, unsigned int* __restrict__ pair, int n_points,
        const int* __restrict__ istart, const int* __restrict__ ilen,
        const int* __restrict__ rb, int4* __restrict__ iv4, int n_intervals,
        uint4* __restrict__ zbuf, int zb_n16) {
    __shared__ float tile[32][33];
    const int bid = blockIdx.x;
    const int tid = threadIdx.x;

    if (bid < TF_BLOCKS) {
        const int bn  = bid / (TF_BX * TF_BY);
        const int r   = bid - bn * (TF_BX * TF_BY);
        const int c0  = (r / TF_BX) * 32;
        const int hw0 = (r - (r / TF_BX) * TF_BX) * 32;
        const int x = tid & 31, y = tid >> 5;           // y in 0..7
        const float* src = feat + ((size_t)bn * C_ + c0) * HW_ + hw0;
        #pragma unroll
        for (int yy = y; yy < 32; yy += 8)
            tile[yy][x] = src[(size_t)yy * HW_ + x];     // coalesced along hw
        __syncthreads();
        __hip_bfloat16* dst = featT + ((size_t)bn * HW_ + hw0) * C_ + c0;
        #pragma unroll
        for (int yy = y; yy < 32; yy += 8)
            dst[(size_t)yy * C_ + x] = __float2bfloat16(tile[x][yy]);  // coalesced along c
    } else if (bid < TF_BLOCKS + PG_BLOCKS) {
        const int t = (bid - TF_BLOCKS) * 256 + tid;
        const int stride = PG_BLOCKS * 256;
        for (int base = t; base < n_points; base += 4 * stride) {
            int ii[4], idx[4], rfv[4];
            float v[4];
            #pragma unroll
            for (int u = 0; u < 4; ++u) {
                ii[u] = base + u * stride;
                const int cl = ii[u] < n_points ? ii[u] : base;  // clamp addr
                idx[u] = rd[cl];
                rfv[u] = rf[cl];
            }
            #pragma unroll
            for (int u = 0; u < 4; ++u) v[u] = depth[idx[u]];    // 4 gathers in flight
            #pragma unroll
            for (int u = 0; u < 4; ++u)
                if (ii[u] < n_points)
                    pair[ii[u]] = (f2bf_rne(v[u]) << 16) | (unsigned)rfv[u];
        }
    } else if (bid < TF_BLOCKS + PG_BLOCKS + IV_BLOCKS) {
        const int ivl = (bid - TF_BLOCKS - PG_BLOCKS) * 256 + tid;
        if (ivl < n_intervals) {
            const int s = istart[ivl];
            iv4[ivl] = make_int4(s, ilen[ivl], rb[s], 0);
        }
    } else {
        int i = (bid - TF_BLOCKS - PG_BLOCKS - IV_BLOCKS) * 256 + tid;
        for (; i < zb_n16; i += ZB_BLOCKS * 256)
            zbuf[i] = make_uint4(0u, 0u, 0u, 0u);
    }
}

// ---------------------------------------------------------------------------
// Main: TWO blocks per interval group — half = blockIdx.x & 1 selects which
// 64 channels; blockIdx parity -> XCD parity, so each XCD gathers from a
// 4.33 MB featT half-table that fits its 4 MB L2 (r7-proven, 51us -> <42).
// Per wave: 8 groups x 8 lanes; lane owns 8 channels of its half (uint4 =
// bf16x8 = 128B half-row per group). Group g owns points i ≡ g (mod 8),
// 4 slots/iteration. Per slot now ONE stream load (pair = bf16 d | rf16)
// feeding the feat gather — single 2-level chain, 4 independent per wave.
// Prologue: one int4 load (start,len,cell) — no dependent chain.
// Tail: clamp addr, multiply by 0 (r2/r4-proven). Store: grp 0 packs bf16x8
// -> uint4 -> 128B contiguous per (ivl, half) (proven-clean store pattern).
// ---------------------------------------------------------------------------
__global__ __launch_bounds__(256) void bevpool_half_k(
        const unsigned int* __restrict__ pair,
        const uint4* __restrict__ featT,
        const int4* __restrict__ iv4,
        unsigned short* __restrict__ cellbuf,
        int n_intervals) {
    const int half = blockIdx.x & 1;
    const int widx = threadIdx.x >> 6;             // 0..3
    const int ivl  = (blockIdx.x >> 1) * 4 + widx; // interval
    if (ivl >= n_intervals) return;
    const int lane = threadIdx.x & 63;
    const int grp  = lane >> 3;        // 0..7: point residue class (mod 8)
    const int sl   = lane & 7;         // channel chunk within half

    const int4 v    = iv4[ivl];
    const int start = v.x;
    const int end   = v.x + v.y;
    const int cell  = v.z;

    float acc[8] = {0.f, 0.f, 0.f, 0.f, 0.f, 0.f, 0.f, 0.f};
    const size_t hoff = (size_t)(half * 8 + sl);   // uint4 offset within 256B row

    for (int i = start + grp; i < end; i += 32) {
        int cl_[4];
        unsigned pr_[4];
        float d_[4];
        uint4 f_[4];
        #pragma unroll
        for (int u = 0; u < 4; ++u) {
            const int ii = i + 8 * u;
            cl_[u] = (ii < end) ? ii : i;          // clamp to valid address
        }
        #pragma unroll
        for (int u = 0; u < 4; ++u) pr_[u] = pair[cl_[u]];   // 1 stream load/slot
        #pragma unroll
        for (int u = 0; u < 4; ++u) d_[u] = __uint_as_float(pr_[u] & 0xffff0000u);
        #pragma unroll
        for (int u = 1; u < 4; ++u) d_[u] = (i + 8 * u < end) ? d_[u] : 0.f;
        #pragma unroll
        for (int u = 0; u < 4; ++u)
            f_[u] = featT[(size_t)(pr_[u] & 0xffffu) * 16 + hoff];
        #pragma unroll
        for (int u = 0; u < 4; ++u) {
            const float d = d_[u];
            acc[0] = fmaf(d, __uint_as_float(f_[u].x << 16),         acc[0]);
            acc[1] = fmaf(d, __uint_as_float(f_[u].x & 0xffff0000u), acc[1]);
            acc[2] = fmaf(d, __uint_as_float(f_[u].y << 16),         acc[2]);
            acc[3] = fmaf(d, __uint_as_float(f_[u].y & 0xffff0000u), acc[3]);
            acc[4] = fmaf(d, __uint_as_float(f_[u].z << 16),         acc[4]);
            acc[5] = fmaf(d, __uint_as_float(f_[u].z & 0xffff0000u), acc[5]);
            acc[6] = fmaf(d, __uint_as_float(f_[u].w << 16),         acc[6]);
            acc[7] = fmaf(d, __uint_as_float(f_[u].w & 0xffff0000u), acc[7]);
        }
    }

    // combine the 8 groups' partial sums (same channels, different points)
    #pragma unroll
    for (int c = 0; c < 8; ++c) {
        acc[c] += __shfl_down(acc[c], 32);
        acc[c] += __shfl_down(acc[c], 16);
        acc[c] += __shfl_down(acc[c], 8);
    }

    if (grp == 0) {
        uint4 p;
        p.x = f2bf_rne(acc[0]) | (f2bf_rne(acc[1]) << 16);
        p.y = f2bf_rne(acc[2]) | (f2bf_rne(acc[3]) << 16);
        p.z = f2bf_rne(acc[4]) | (f2bf_rne(acc[5]) << 16);
        p.w = f2bf_rne(acc[6]) | (f2bf_rne(acc[7]) << 16);
        *(uint4*)(cellbuf + (size_t)cell * C_ + half * 64 + sl * 8) = p;
    }
}

// ---------------------------------------------------------------------------
// cellbuf [B, SPAT, C] bf16 -> out [B, C, SPAT] f32 (both sides coalesced)
// ---------------------------------------------------------------------------
__global__ __launch_bounds__(256) void transpose_out_bf16_k(const unsigned short* __restrict__ cellbuf,
                                                            float* __restrict__ out) {
    __shared__ float tile[32][33];
    const int b   = blockIdx.z;
    const int sp0 = blockIdx.x * 32;
    const int c0  = blockIdx.y * 32;
    const int x = threadIdx.x;
    const int y = threadIdx.y;

    const unsigned short* src = cellbuf + ((size_t)b * SPAT_ + sp0) * C_ + c0;
    #pragma unroll
    for (int yy = y; yy < 32; yy += 8)
        tile[yy][x] = __uint_as_float((unsigned int)src[(size_t)yy * C_ + x] << 16);
    __syncthreads();
    float* dst = out + ((size_t)b * C_ + c0) * SPAT_ + sp0;
    #pragma unroll
    for (int yy = y; yy < 32; yy += 8)
        dst[(size_t)yy * SPAT_ + x] = tile[x][yy];   // 128B contiguous per row
}

// ---------------------------------------------------------------------------
// Fallback (ws too small): original-layout reads, scattered stores.
// ---------------------------------------------------------------------------
__global__ __launch_bounds__(256) void bevpool_fallback_k(const float* __restrict__ depth,
                                                          const float* __restrict__ feat,
                                                          const int* __restrict__ rd_arr,
                                                          const int* __restrict__ rf_arr,
                                                          const int* __restrict__ rb,
                                                          const int* __restrict__ istart,
                                                          const int* __restrict__ ilen,
                                                          float* __restrict__ out,
                                                          int n_intervals) {
    const int wave = (int)((blockIdx.x * blockDim.x + threadIdx.x) >> 6);
    const int lane = threadIdx.x & 63;
    if (wave >= n_intervals) return;
    const int start = istart[wave];
    const int len   = ilen[wave];
    const int cell  = rb[start];
    float ax = 0.f, ay = 0.f;
    const int end = start + len;
    for (int i = start; i < end; ++i) {
        const int rfi = rf_arr[i];
        const int bn  = rfi / HW_;
        const int hw  = rfi - bn * HW_;
        const float d = depth[rd_arr[i]];
        const float* frow = feat + (size_t)bn * (C_ * HW_) + hw;
        ax = fmaf(d, frow[(size_t)(2 * lane)     * HW_], ax);
        ay = fmaf(d, frow[(size_t)(2 * lane + 1) * HW_], ay);
    }
    const int b  = cell >> 14;
    const int sp = cell & (SPAT_ - 1);
    float* o = out + (size_t)b * ((size_t)C_ * SPAT_) + sp;
    o[(size_t)(2 * lane)     * SPAT_] = ax;
    o[(size_t)(2 * lane + 1) * SPAT_] = ay;
}

extern "C" void kernel_launch(void* const* d_in, const int* in_sizes, int n_in,
                              void* d_out, int out_size, void* d_ws, size_t ws_size,
                              hipStream_t stream) {
    const float* depth  = (const float*)d_in[0];
    const float* feat   = (const float*)d_in[1];
    const int*   rd     = (const int*)d_in[2];
    const int*   rf     = (const int*)d_in[3];
    const int*   rb     = (const int*)d_in[4];
    const int*   istart = (const int*)d_in[5];
    const int*   ilen   = (const int*)d_in[6];
    float*       out    = (float*)d_out;
    const int n_intervals = in_sizes[5];
    const int n_points    = in_sizes[2];

    const size_t cellbuf_bytes = (size_t)CELLS_ * C_ * sizeof(unsigned short);    // 8.39 MB
    const size_t featT_bytes   = (size_t)BN_ * HW_ * C_ * sizeof(__hip_bfloat16); // 8.65 MB
    const size_t pair_bytes    = ((size_t)n_points * sizeof(unsigned int) + 15) & ~(size_t)15;
    const size_t iv4_bytes     = (size_t)CELLS_ * sizeof(int4);                   // 0.52 MB

    if (ws_size >= cellbuf_bytes + featT_bytes + pair_bytes + iv4_bytes &&
        n_intervals <= CELLS_) {
        unsigned short* cellbuf = (unsigned short*)d_ws;
        __hip_bfloat16* featT   = (__hip_bfloat16*)((char*)d_ws + cellbuf_bytes);
        unsigned int*   pair    = (unsigned int*)((char*)d_ws + cellbuf_bytes + featT_bytes);
        int4*           iv4     = (int4*)((char*)d_ws + cellbuf_bytes + featT_bytes + pair_bytes);

        const int prep_blocks = TF_BLOCKS + PG_BLOCKS + IV_BLOCKS + ZB_BLOCKS;
        prep_k<<<prep_blocks, 256, 0, stream>>>(
            feat, featT, depth, rd, rf, pair, n_points,
            istart, ilen, rb, iv4, n_intervals,
            (uint4*)cellbuf, (int)(cellbuf_bytes / 16));

        const int blocks2 = 2 * ((n_intervals + 3) / 4);   // (interval-group, half)
        bevpool_half_k<<<blocks2, 256, 0, stream>>>(
            pair, (const uint4*)featT, iv4, cellbuf, n_intervals);

        {
            dim3 g(SPAT_ / 32, C_ / 32, 2);
            dim3 b(32, 8);
            transpose_out_bf16_k<<<g, b, 0, stream>>>(cellbuf, out);
        }
    } else {
        hipMemsetAsync(out, 0, (size_t)out_size * sizeof(float), stream);
        const int blocks = (n_intervals + 3) / 4;
        bevpool_fallback_k<<<blocks, 256, 0, stream>>>(
            depth, feat, rd, rf, rb, istart, ilen, out, n_intervals);
    }
}

// Round 11
// 59.073 us; speedup vs baseline: 2.6327x; 1.0718x over previous
//
#include <hip/hip_runtime.h>
#include <hip/hip_bf16.h>

// Problem constants (from reference):
// B=2, N=6, D=120, H=32, W=88, C=128, Z=1, HO=128, WO=128
#define HW_    2816
#define C_     128
#define BN_    12
#define SPAT_  16384
#define CELLS_ 32768
#define CB_    64          // cells per main block (64 lanes x 4B = 256B clean stores)

// prep_k block-range dispatch
#define TF_BX     88                       // HW_/32
#define TF_BY     4                        // C_/32
#define TF_BLOCKS (TF_BX * TF_BY * BN_)    // 4224 transpose tiles
#define PG_BLOCKS 1024                     // pregather/pack
#define IV_BLOCKS 128                      // 128*256 = 32768 >= n_intervals

// round-to-nearest-even f32 -> bf16 (as uint in [0,0xffff]); finite values
__device__ __forceinline__ unsigned int f2bf_rne(float x) {
    const unsigned int u = __float_as_uint(x);
    return (u + 0x7fffu + ((u >> 16) & 1u)) >> 16;
}

// ---------------------------------------------------------------------------
// Fused prep:
//   [0, TF)      feat [BN,C,HW] f32 -> featT [BN,HW,C] bf16
//   [TF, +PG)    pair[i] = bf16(depth[rd[i]])<<16 | rf[i]   (rf < 33792 fits u16)
//   [.., +IV)    iv4[ivl] = {start, len, cell, 0};  map[cell] = ivl, and each
//                thread fills the gap (cell, next_cell) with -1 -> race-free
//                full cell->interval map (rb sorted).
// ---------------------------------------------------------------------------
__global__ __launch_bounds__(256) void prep_k(
        const float* __restrict__ feat, __hip_bfloat16* __restrict__ featT,
        const float* __restrict__ depth, const int* __restrict__ rd,
        const int* __restrict__ rf, unsigned int* __restrict__ pair, int n_points,
        const int* __restrict__ istart, const int* __restrict__ ilen,
        const int* __restrict__ rb, int4* __restrict__ iv4,
        int* __restrict__ map, int n_intervals) {
    __shared__ float tile[32][33];
    const int bid = blockIdx.x;
    const int tid = threadIdx.x;

    if (bid < TF_BLOCKS) {
        const int bn  = bid / (TF_BX * TF_BY);
        const int r   = bid - bn * (TF_BX * TF_BY);
        const int c0  = (r / TF_BX) * 32;
        const int hw0 = (r - (r / TF_BX) * TF_BX) * 32;
        const int x = tid & 31, y = tid >> 5;           // y in 0..7
        const float* src = feat + ((size_t)bn * C_ + c0) * HW_ + hw0;
        #pragma unroll
        for (int yy = y; yy < 32; yy += 8)
            tile[yy][x] = src[(size_t)yy * HW_ + x];     // coalesced along hw
        __syncthreads();
        __hip_bfloat16* dst = featT + ((size_t)bn * HW_ + hw0) * C_ + c0;
        #pragma unroll
        for (int yy = y; yy < 32; yy += 8)
            dst[(size_t)yy * C_ + x] = __float2bfloat16(tile[x][yy]);  // coalesced along c
    } else if (bid < TF_BLOCKS + PG_BLOCKS) {
        const int t = (bid - TF_BLOCKS) * 256 + tid;
        const int stride = PG_BLOCKS * 256;
        for (int base = t; base < n_points; base += 4 * stride) {
            int ii[4], idx[4], rfv[4];
            float v[4];
            #pragma unroll
            for (int u = 0; u < 4; ++u) {
                ii[u] = base + u * stride;
                const int cl = ii[u] < n_points ? ii[u] : base;  // clamp addr
                idx[u] = rd[cl];
                rfv[u] = rf[cl];
            }
            #pragma unroll
            for (int u = 0; u < 4; ++u) v[u] = depth[idx[u]];    // 4 gathers in flight
            #pragma unroll
            for (int u = 0; u < 4; ++u)
                if (ii[u] < n_points)
                    pair[ii[u]] = (f2bf_rne(v[u]) << 16) | (unsigned)rfv[u];
        }
    } else {
        const int ivl = (bid - TF_BLOCKS - PG_BLOCKS) * 256 + tid;
        if (ivl < n_intervals) {
            const int s = istart[ivl];
            const int c = rb[s];
            iv4[ivl] = make_int4(s, ilen[ivl], c, 0);
            map[c] = ivl;
            const int cnext = (ivl + 1 < n_intervals) ? rb[istart[ivl + 1]] : CELLS_;
            for (int cc = c + 1; cc < cnext; ++cc) map[cc] = -1;   // gaps (~none)
            if (ivl == 0) for (int cc = 0; cc < c; ++cc) map[cc] = -1;
        }
    }
}

// ---------------------------------------------------------------------------
// Main, direct-to-out: block = (64-cell range, channel-half). blockIdx.x&1 ->
// XCD parity, so each XCD gathers only its 4.33 MB featT half (fits 4 MB L2,
// r7-proven). 16 waves x 4 sequential cells; per interval the r10-proven
// gather loop: ONE pair load/slot (bf16 d | rf16) feeding the featT gather,
// 4 slots in flight; 8 groups x 8 lanes, lane owns 8 channels of the half.
// Results staged f32 in LDS [64][68]; cooperative store writes each channel
// row as 64 lanes x 4B = 256B FULLY CONTIGUOUS per instruction (r6-proven
// clean granularity; 64B segments are 17x amplified, r5). Every out element
// written exactly once (empty cells -> LDS zeros) => no zero pass, no
// cellbuf, no transpose_out.
// ---------------------------------------------------------------------------
__global__ __launch_bounds__(1024, 4) void bevpool_cells_k(
        const unsigned int* __restrict__ pair,
        const uint4* __restrict__ featT,
        const int4* __restrict__ iv4,
        const int* __restrict__ map,
        float* __restrict__ out) {
    __shared__ float lds[CB_][68];   // pad 68: rows 16B-aligned; minor read conflict ok
    const int half  = blockIdx.x & 1;
    const int cb    = blockIdx.x >> 1;        // 0..511
    const int cell0 = cb * CB_;
    const int tid   = threadIdx.x;

    #pragma unroll
    for (int i = tid; i < CB_ * 68; i += 1024) (&lds[0][0])[i] = 0.f;
    __syncthreads();

    const int widx = tid >> 6;       // 0..15
    const int lane = tid & 63;
    const int grp  = lane >> 3;      // 0..7: point residue class (mod 8)
    const int sl   = lane & 7;       // channel chunk within half
    const size_t hoff = (size_t)(half * 8 + sl);
    const int cl0  = widx * 4;       // this wave's first local cell

    const int4 m4 = *(const int4*)&map[cell0 + cl0];   // 4 interval ids (16B aligned)
    const int m[4] = {m4.x, m4.y, m4.z, m4.w};
    int4 vq[4];
    #pragma unroll
    for (int q = 0; q < 4; ++q) vq[q] = iv4[m[q] < 0 ? 0 : m[q]];  // 4 indep loads

    #pragma unroll
    for (int q = 0; q < 4; ++q) {
        if (m[q] < 0) continue;                    // empty cell: LDS stays zero
        const int start = vq[q].x;
        const int end   = vq[q].x + vq[q].y;

        float acc[8] = {0.f, 0.f, 0.f, 0.f, 0.f, 0.f, 0.f, 0.f};
        for (int i = start + grp; i < end; i += 32) {
            int cl_[4];
            unsigned pr_[4];
            float d_[4];
            uint4 f_[4];
            #pragma unroll
            for (int u = 0; u < 4; ++u) {
                const int ii = i + 8 * u;
                cl_[u] = (ii < end) ? ii : i;      // clamp to valid address
            }
            #pragma unroll
            for (int u = 0; u < 4; ++u) pr_[u] = pair[cl_[u]];  // 1 stream load/slot
            #pragma unroll
            for (int u = 0; u < 4; ++u) d_[u] = __uint_as_float(pr_[u] & 0xffff0000u);
            #pragma unroll
            for (int u = 1; u < 4; ++u) d_[u] = (i + 8 * u < end) ? d_[u] : 0.f;
            #pragma unroll
            for (int u = 0; u < 4; ++u)
                f_[u] = featT[(size_t)(pr_[u] & 0xffffu) * 16 + hoff];
            #pragma unroll
            for (int u = 0; u < 4; ++u) {
                const float d = d_[u];
                acc[0] = fmaf(d, __uint_as_float(f_[u].x << 16),         acc[0]);
                acc[1] = fmaf(d, __uint_as_float(f_[u].x & 0xffff0000u), acc[1]);
                acc[2] = fmaf(d, __uint_as_float(f_[u].y << 16),         acc[2]);
                acc[3] = fmaf(d, __uint_as_float(f_[u].y & 0xffff0000u), acc[3]);
                acc[4] = fmaf(d, __uint_as_float(f_[u].z << 16),         acc[4]);
                acc[5] = fmaf(d, __uint_as_float(f_[u].z & 0xffff0000u), acc[5]);
                acc[6] = fmaf(d, __uint_as_float(f_[u].w << 16),         acc[6]);
                acc[7] = fmaf(d, __uint_as_float(f_[u].w & 0xffff0000u), acc[7]);
            }
        }
        #pragma unroll
        for (int c = 0; c < 8; ++c) {
            acc[c] += __shfl_down(acc[c], 32);
            acc[c] += __shfl_down(acc[c], 16);
            acc[c] += __shfl_down(acc[c], 8);
        }
        if (grp == 0) {
            #pragma unroll
            for (int c = 0; c < 8; ++c) lds[cl0 + q][sl * 8 + c] = acc[c];
        }
    }
    __syncthreads();

    // cooperative store: wave instr = 64 lanes x 4B = 256B contiguous (clean)
    const int cl  = tid & 63;
    const int chb = tid >> 6;                 // 0..15
    const int b   = cell0 >> 14;              // cell0 / SPAT_
    const int sp0 = cell0 & (SPAT_ - 1);
    float* obase = out + ((size_t)b * C_ + half * 64) * SPAT_ + sp0;
    #pragma unroll
    for (int it = 0; it < 4; ++it) {
        const int ch = chb + 16 * it;         // 0..63 within the half
        obase[(size_t)ch * SPAT_ + cl] = lds[cl][ch];
    }
}

// ---------------------------------------------------------------------------
// Fallback (ws too small): original-layout reads, scattered stores.
// ---------------------------------------------------------------------------
__global__ __launch_bounds__(256) void bevpool_fallback_k(const float* __restrict__ depth,
                                                          const float* __restrict__ feat,
                                                          const int* __restrict__ rd_arr,
                                                          const int* __restrict__ rf_arr,
                                                          const int* __restrict__ rb,
                                                          const int* __restrict__ istart,
                                                          const int* __restrict__ ilen,
                                                          float* __restrict__ out,
                                                          int n_intervals) {
    const int wave = (int)((blockIdx.x * blockDim.x + threadIdx.x) >> 6);
    const int lane = threadIdx.x & 63;
    if (wave >= n_intervals) return;
    const int start = istart[wave];
    const int len   = ilen[wave];
    const int cell  = rb[start];
    float ax = 0.f, ay = 0.f;
    const int end = start + len;
    for (int i = start; i < end; ++i) {
        const int rfi = rf_arr[i];
        const int bn  = rfi / HW_;
        const int hw  = rfi - bn * HW_;
        const float d = depth[rd_arr[i]];
        const float* frow = feat + (size_t)bn * (C_ * HW_) + hw;
        ax = fmaf(d, frow[(size_t)(2 * lane)     * HW_], ax);
        ay = fmaf(d, frow[(size_t)(2 * lane + 1) * HW_], ay);
    }
    const int b  = cell >> 14;
    const int sp = cell & (SPAT_ - 1);
    float* o = out + (size_t)b * ((size_t)C_ * SPAT_) + sp;
    o[(size_t)(2 * lane)     * SPAT_] = ax;
    o[(size_t)(2 * lane + 1) * SPAT_] = ay;
}

extern "C" void kernel_launch(void* const* d_in, const int* in_sizes, int n_in,
                              void* d_out, int out_size, void* d_ws, size_t ws_size,
                              hipStream_t stream) {
    const float* depth  = (const float*)d_in[0];
    const float* feat   = (const float*)d_in[1];
    const int*   rd     = (const int*)d_in[2];
    const int*   rf     = (const int*)d_in[3];
    const int*   rb     = (const int*)d_in[4];
    const int*   istart = (const int*)d_in[5];
    const int*   ilen   = (const int*)d_in[6];
    float*       out    = (float*)d_out;
    const int n_intervals = in_sizes[5];
    const int n_points    = in_sizes[2];

    const size_t featT_bytes = (size_t)BN_ * HW_ * C_ * sizeof(__hip_bfloat16); // 8.65 MB
    const size_t pair_bytes  = ((size_t)n_points * sizeof(unsigned int) + 15) & ~(size_t)15;
    const size_t iv4_bytes   = (size_t)CELLS_ * sizeof(int4);                   // 0.52 MB
    const size_t map_bytes   = (size_t)CELLS_ * sizeof(int);                    // 0.13 MB

    if (ws_size >= featT_bytes + pair_bytes + iv4_bytes + map_bytes &&
        n_intervals <= CELLS_) {
        __hip_bfloat16* featT = (__hip_bfloat16*)d_ws;
        unsigned int*   pair  = (unsigned int*)((char*)d_ws + featT_bytes);
        int4*           iv4   = (int4*)((char*)d_ws + featT_bytes + pair_bytes);
        int*            map   = (int*)((char*)d_ws + featT_bytes + pair_bytes + iv4_bytes);

        const int prep_blocks = TF_BLOCKS + PG_BLOCKS + IV_BLOCKS;
        prep_k<<<prep_blocks, 256, 0, stream>>>(
            feat, featT, depth, rd, rf, pair, n_points,
            istart, ilen, rb, iv4, map, n_intervals);

        bevpool_cells_k<<<(CELLS_ / CB_) * 2, 1024, 0, stream>>>(
            pair, (const uint4*)featT, iv4, map, out);
    } else {
        hipMemsetAsync(out, 0, (size_t)out_size * sizeof(float), stream);
        const int blocks = (n_intervals + 3) / 4;
        bevpool_fallback_k<<<blocks, 256, 0, stream>>>(
            depth, feat, rd, rf, rb, istart, ilen, out, n_intervals);
    }
}